// Round 3
// baseline (626.114 us; speedup 1.0000x reference)
//
#include <hip/hip_runtime.h>

// GumbelCodebook: y = one_hot(argmax(logits+gumbel)), z = codebook[argmax]
// Shapes: logits/gumbel [8,4096,2048] f32, codebook [2048,256] f32
// Outputs concatenated in d_out: z [8,4096,256] then y [8,4096,2048], f32.
//
// v3b: phase-split into copy-shaped streams (v3 + compile fix: nontemporal
// store needs a native vector type, not HIP_vector_type float4).
//  - hipMemsetAsync zeroes the 256MB y region (pure write stream, blit speed).
//  - Kernel is nearly pure-read: 512MB logits+gumbel in, 32MB z out (NT
//    stores), plus ONE 4-byte y[amax]=1.0 per token.
//  - One wave per token (64 lanes x 32 codes), butterfly argmax, no LDS.
//  - Grid-stride with 2048 persistent blocks.

#define NUM_CODES 2048
#define CODE_DIM  256
#define BLOCK     256
#define WAVES_PER_BLOCK (BLOCK / 64)

typedef float vfloat4 __attribute__((ext_vector_type(4)));  // native vec type

__device__ __forceinline__ void upd(float4 l, float4 g, int base,
                                    float& best, int& bestIdx) {
    float s0 = l.x + g.x;
    float s1 = l.y + g.y;
    float s2 = l.z + g.z;
    float s3 = l.w + g.w;
    if (s0 > best) { best = s0; bestIdx = base + 0; }
    if (s1 > best) { best = s1; bestIdx = base + 1; }
    if (s2 > best) { best = s2; bestIdx = base + 2; }
    if (s3 > best) { best = s3; bestIdx = base + 3; }
}

__global__ __launch_bounds__(BLOCK, 8) void gumbel_argmax_z_kernel(
    const float* __restrict__ logits,
    const float* __restrict__ gumbel,
    const float* __restrict__ codebook,
    float* __restrict__ z_out,   // [tokens, CODE_DIM]
    float* __restrict__ y_out,   // [tokens, NUM_CODES] (pre-zeroed by memset)
    int tokens)
{
    const int lane = threadIdx.x & 63;
    const int wave = threadIdx.x >> 6;
    const int stride = gridDim.x * WAVES_PER_BLOCK;

    for (int token = blockIdx.x * WAVES_PER_BLOCK + wave; token < tokens;
         token += stride) {
        const size_t row_off = (size_t)token * NUM_CODES;
        const float4* lrow = (const float4*)(logits + row_off);
        const float4* grow = (const float4*)(gumbel + row_off);

        // --- per-lane argmax over 32 codes, two batches of 4 vec-pairs so
        // 8 float4 loads are in flight per batch. For fixed lane the index
        // (c*64+lane)*4 increases with c, so strict '>' keeps the first
        // (lowest-index) max within the lane — matching jnp.argmax. ---
        float best = -INFINITY;
        int bestIdx = NUM_CODES;  // sentinel
#pragma unroll
        for (int h = 0; h < 2; ++h) {
            const int c0 = h * 4;
            float4 l0 = lrow[(c0 + 0) * 64 + lane];
            float4 g0 = grow[(c0 + 0) * 64 + lane];
            float4 l1 = lrow[(c0 + 1) * 64 + lane];
            float4 g1 = grow[(c0 + 1) * 64 + lane];
            float4 l2 = lrow[(c0 + 2) * 64 + lane];
            float4 g2 = grow[(c0 + 2) * 64 + lane];
            float4 l3 = lrow[(c0 + 3) * 64 + lane];
            float4 g3 = grow[(c0 + 3) * 64 + lane];
            upd(l0, g0, ((c0 + 0) * 64 + lane) * 4, best, bestIdx);
            upd(l1, g1, ((c0 + 1) * 64 + lane) * 4, best, bestIdx);
            upd(l2, g2, ((c0 + 2) * 64 + lane) * 4, best, bestIdx);
            upd(l3, g3, ((c0 + 3) * 64 + lane) * 4, best, bestIdx);
        }

        // --- wave butterfly argmax; lower index wins ties. ---
#pragma unroll
        for (int m = 1; m < 64; m <<= 1) {
            float ob = __shfl_xor(best, m, 64);
            int   oi = __shfl_xor(bestIdx, m, 64);
            if (ob > best || (ob == best && oi < bestIdx)) {
                best = ob; bestIdx = oi;
            }
        }
        const int amax = bestIdx;

        // --- z = codebook[amax]: one float4 per lane, non-temporal (z is
        // never re-read; keep L2/L3 for the input streams). Codebook is
        // 2MB -> L2-resident. Native vec type for the NT builtin. ---
        const vfloat4* crow =
            (const vfloat4*)(codebook + (size_t)amax * CODE_DIM);
        vfloat4* zrow = (vfloat4*)(z_out + (size_t)token * CODE_DIM);
        vfloat4 zval = crow[lane];
        __builtin_nontemporal_store(zval, &zrow[lane]);

        // --- y: single element patch; bulk zeros were done by memset. ---
        if (lane == 0) {
            y_out[row_off + amax] = 1.0f;
        }
    }
}

extern "C" void kernel_launch(void* const* d_in, const int* in_sizes, int n_in,
                              void* d_out, int out_size, void* d_ws, size_t ws_size,
                              hipStream_t stream) {
    const float* logits   = (const float*)d_in[0];
    const float* gumbel   = (const float*)d_in[1];
    const float* codebook = (const float*)d_in[2];

    const int tokens = in_sizes[0] / NUM_CODES;  // 8*4096 = 32768

    float* z_out = (float*)d_out;                               // [tokens, 256]
    float* y_out = (float*)d_out + (size_t)tokens * CODE_DIM;   // [tokens, 2048]

    // Phase 1: zero the one-hot output as a pure write stream.
    (void)hipMemsetAsync(y_out, 0,
                         (size_t)tokens * NUM_CODES * sizeof(float), stream);

    // Phase 2: read-dominant argmax kernel; writes only z + one float per row.
    int blocks = (tokens + WAVES_PER_BLOCK - 1) / WAVES_PER_BLOCK;
    if (blocks > 2048) blocks = 2048;  // persistent grid-stride
    gumbel_argmax_z_kernel<<<blocks, BLOCK, 0, stream>>>(
        logits, gumbel, codebook, z_out, y_out, tokens);
}